// Round 1
// baseline (1756.236 us; speedup 1.0000x reference)
//
#include <hip/hip_runtime.h>

#define BB 32
#define CKD 64
#define CC 8
#define KK 8
#define TT 64

static __device__ __forceinline__ float4 ld4(const float* p){ return *(const float4*)p; }

// ---------------- trig tables: per level, tbl[t*64+x] = (cos, sin)(2*pi*x*t/n_h), zero for x>=l
__global__ __launch_bounds__(256) void gen_tbl_k(float2* __restrict__ base) {
    int lev = blockIdx.y;
    int nh = 4096 >> lev;
    int idx = blockIdx.x * 256 + threadIdx.x;
    if (idx >= nh * 64) return;
    int t = idx >> 6, x = idx & 63;
    int l = nh / 2 + 1; if (l > 64) l = 64;
    float c = 0.f, s = 0.f;
    if (x < l) {
        int r = (x * t) & (nh - 1);
        float th = 6.283185307179586f * ((float)r / (float)nh);
        sincosf(th, &s, &c);
    }
    size_t off = 64ull * (8192u - (8192u >> lev));
    base[off + idx] = make_float2(c, s);
}

// ---------------- decompose: x[b,2t,c,:],x[b,2t+1,c,:] -> d,s via ec_d/ec_s (16x8)
__global__ __launch_bounds__(256) void decomp_k(const float* __restrict__ xin,
        const float* __restrict__ ecd, const float* __restrict__ ecs,
        float* __restrict__ dslot, float* __restrict__ sslot, int nh) {
    int idx = blockIdx.x * 256 + threadIdx.x;
    if (idx >= BB * nh * CC) return;
    int c = idx & 7;
    int t = (idx >> 3) % nh;
    int b = idx / (nh * CC);
    const float* p0 = xin + ((size_t)b * 2 * nh + 2 * t) * CKD + c * KK;
    float xa[16];
    float4 v;
    v = ld4(p0);      xa[0]=v.x; xa[1]=v.y; xa[2]=v.z; xa[3]=v.w;
    v = ld4(p0+4);    xa[4]=v.x; xa[5]=v.y; xa[6]=v.z; xa[7]=v.w;
    v = ld4(p0+64);   xa[8]=v.x; xa[9]=v.y; xa[10]=v.z; xa[11]=v.w;
    v = ld4(p0+68);   xa[12]=v.x; xa[13]=v.y; xa[14]=v.z; xa[15]=v.w;
    float dd[8], ss[8];
    #pragma unroll
    for (int m = 0; m < 8; m++) { dd[m] = 0.f; ss[m] = 0.f; }
    #pragma unroll
    for (int j = 0; j < 16; j++) {
        float xv = xa[j];
        #pragma unroll
        for (int m = 0; m < 8; m++) {
            dd[m] = fmaf(xv, ecd[j*8+m], dd[m]);
            ss[m] = fmaf(xv, ecs[j*8+m], ss[m]);
        }
    }
    size_t ob = ((size_t)b * nh + t) * CKD + c * KK;
    *(float4*)(dslot+ob)   = make_float4(dd[0],dd[1],dd[2],dd[3]);
    *(float4*)(dslot+ob+4) = make_float4(dd[4],dd[5],dd[6],dd[7]);
    *(float4*)(sslot+ob)   = make_float4(ss[0],ss[1],ss[2],ss[3]);
    *(float4*)(sslot+ob+4) = make_float4(ss[4],ss[5],ss[6],ss[7]);
}

// ---------------- forward truncated DFT: xf[b,x,i] = sum_t v[b,t,i]*(cos, -sin)
// block = (chunk, b, which-of-d/s); 256 thr = 16 i-groups x 16 x-groups; atomics across chunks
__global__ __launch_bounds__(256) void fft_fwd_k(const float* __restrict__ vd,
        const float* __restrict__ vs, const float2* __restrict__ tbl,
        float2* __restrict__ xfd, float2* __restrict__ xfs,
        int nh, int tpc) {
    __shared__ float4 vt4[TT*CKD/4];   // 16 KB  value tile [t][i]
    __shared__ float4 tg4[TT*CKD/2];   // 32 KB  trig tile  [t][x] (float2)
    float* vt = (float*)vt4;
    float2* tg = (float2*)tg4;
    int b = blockIdx.y;
    const float* V = (blockIdx.z ? vs : vd) + (size_t)b * nh * CKD;
    float2* XF = (blockIdx.z ? xfs : xfd) + (size_t)b * 64 * 64;
    int tid = threadIdx.x;
    int tx = tid & 15, ty = tid >> 4;
    int tiles = (nh + TT - 1) / TT;
    int tile0 = blockIdx.x * tpc;
    int tile1 = tile0 + tpc; if (tile1 > tiles) tile1 = tiles;
    float2 acc[4][4];
    #pragma unroll
    for (int a = 0; a < 4; a++)
        #pragma unroll
        for (int i = 0; i < 4; i++) acc[a][i] = make_float2(0.f, 0.f);
    for (int tile = tile0; tile < tile1; tile++) {
        int tbase = tile * TT;
        __syncthreads();
        #pragma unroll
        for (int q = 0; q < 4; q++) {
            int fi = tid + 256*q;
            int r = fi >> 4;
            float4 v = make_float4(0.f,0.f,0.f,0.f);
            if (tbase + r < nh) v = ld4(V + (size_t)(tbase + r)*CKD + (fi & 15)*4);
            vt4[fi] = v;
        }
        const float4* tsrc = (const float4*)(tbl + (size_t)tbase * CKD);
        #pragma unroll
        for (int q = 0; q < 8; q++) {
            int fi = tid + 256*q;
            int r = fi >> 5;
            float4 v = make_float4(0.f,0.f,0.f,0.f);
            if (tbase + r < nh) v = tsrc[fi];
            tg4[fi] = v;
        }
        __syncthreads();
        #pragma unroll 4
        for (int t = 0; t < TT; t++) {
            float4 vv  = *(float4*)&vt[t*CKD + tx*4];
            float4 c01 = *(float4*)&tg[t*CKD + ty*4];
            float4 c23 = *(float4*)&tg[t*CKD + ty*4 + 2];
            float cx[4] = {c01.x, c01.z, c23.x, c23.z};
            float sx[4] = {c01.y, c01.w, c23.y, c23.w};
            float vr[4] = {vv.x, vv.y, vv.z, vv.w};
            #pragma unroll
            for (int a = 0; a < 4; a++)
                #pragma unroll
                for (int i = 0; i < 4; i++) {
                    acc[a][i].x = fmaf(cx[a],  vr[i], acc[a][i].x);
                    acc[a][i].y = fmaf(-sx[a], vr[i], acc[a][i].y);
                }
        }
    }
    int x0 = ty*4, i0 = tx*4;
    if (gridDim.x == 1) {
        #pragma unroll
        for (int a = 0; a < 4; a++)
            #pragma unroll
            for (int i = 0; i < 4; i++)
                XF[(x0+a)*64 + i0 + i] = acc[a][i];
    } else {
        #pragma unroll
        for (int a = 0; a < 4; a++)
            #pragma unroll
            for (int i = 0; i < 4; i++) {
                float* pp = (float*)&XF[(x0+a)*64 + i0 + i];
                atomicAdd(pp,   acc[a][i].x);
                atomicAdd(pp+1, acc[a][i].y);
            }
    }
}

// ---------------- spectral mix: per mode x, of = xf * W (complex), write (A, Bn) pre-scaled for irfft
__global__ __launch_bounds__(256) void mix_k(const float2* __restrict__ xfd,
        const float2* __restrict__ xfs,
        const float* __restrict__ wAr, const float* __restrict__ wAi,
        const float* __restrict__ wBr, const float* __restrict__ wBi,
        const float* __restrict__ wCr, const float* __restrict__ wCi,
        float2* __restrict__ ofud, float2* __restrict__ ofus, int nh) {
    int x = blockIdx.x;
    int tid = threadIdx.x;
    int o = tid & 63, wq = tid >> 6;
    __shared__ float2 sxd[BB*CKD];     // 16 KB
    __shared__ float2 sxs[BB*CKD];     // 16 KB
    __shared__ float  swt[6][16*CKD];  // 24 KB
    for (int q = tid; q < BB*CKD; q += 256) {
        int b = q >> 6, i = q & 63;
        sxd[q] = xfd[((size_t)b*64 + x)*64 + i];
        sxs[q] = xfs[((size_t)b*64 + x)*64 + i];
    }
    float2 aud[8], aus[8];
    #pragma unroll
    for (int j=0;j<8;j++){ aud[j]=make_float2(0.f,0.f); aus[j]=make_float2(0.f,0.f); }
    for (int ic = 0; ic < 4; ic++) {
        __syncthreads();
        for (int q = tid; q < 16*CKD; q += 256) {
            int ii = q >> 6, oo = q & 63;
            size_t a = ((size_t)(ic*16+ii)*64 + oo)*64 + x;
            swt[0][q] = wAr[a]; swt[1][q] = wAi[a];
            swt[2][q] = wBr[a]; swt[3][q] = wBi[a];
            swt[4][q] = wCr[a]; swt[5][q] = wCi[a];
        }
        __syncthreads();
        #pragma unroll 4
        for (int ii = 0; ii < 16; ii++) {
            float ar = swt[0][ii*64+o], ai_ = swt[1][ii*64+o];
            float br = swt[2][ii*64+o], bi_ = swt[3][ii*64+o];
            float cr = swt[4][ii*64+o], ci_ = swt[5][ii*64+o];
            int i = ic*16 + ii;
            #pragma unroll
            for (int j = 0; j < 8; j++) {
                float2 xd = sxd[(wq*8+j)*64 + i];
                float2 xs = sxs[(wq*8+j)*64 + i];
                aud[j].x += xd.x*ar - xd.y*ai_ + xs.x*br - xs.y*bi_;
                aud[j].y += xd.x*ai_ + xd.y*ar + xs.x*bi_ + xs.y*br;
                aus[j].x += xd.x*cr - xd.y*ci_;
                aus[j].y += xd.x*ci_ + xd.y*cr;
            }
        }
    }
    float w = (x == 0 || 2*x == nh) ? 1.f : 2.f;   // irfft doubling; DC/Nyquist not doubled
    float sc = w / (float)nh;
    #pragma unroll
    for (int j = 0; j < 8; j++) {
        int b = wq*8 + j;
        size_t a = ((size_t)b*64 + x)*64 + o;
        ofud[a] = make_float2(sc*aud[j].x, -sc*aud[j].y);   // (A, Bn)
        ofus[a] = make_float2(sc*aus[j].x, -sc*aus[j].y);
    }
}

// ---------------- inverse truncated DFT: u[b,t,o] = sum_x A[x,o]*cos + Bn[x,o]*sin
__global__ __launch_bounds__(256) void fft_inv_k(const float2* __restrict__ ofud,
        const float2* __restrict__ ofus, const float2* __restrict__ tbl,
        float* __restrict__ uds, float* __restrict__ uss,
        int nh, int l) {
    __shared__ float4 sof4[64*CKD/2];  // 32 KB  [x][o] (A,Bn)
    __shared__ float4 stg4[TT*CKD/2];  // 32 KB  trig tile, XOR-swizzled rows
    float2* sof = (float2*)sof4;
    float2* stg = (float2*)stg4;
    int b = blockIdx.y;
    const float2* OF = (blockIdx.z ? ofus : ofud) + (size_t)b * 64 * 64;
    float* U = (blockIdx.z ? uss : uds) + (size_t)b * nh * CKD;
    int tid = threadIdx.x;
    int tx = tid & 15, ty = tid >> 4;
    int tbase = blockIdx.x * TT;
    #pragma unroll
    for (int q = 0; q < 8; q++) {
        int fi = tid + 256*q;
        int x = fi >> 5;
        float4 v = make_float4(0.f,0.f,0.f,0.f);
        if (x < l) v = ((const float4*)OF)[fi];
        sof4[fi] = v;
    }
    const float4* tsrc = (const float4*)(tbl + (size_t)tbase * CKD);
    #pragma unroll
    for (int q = 0; q < 8; q++) {
        int fi = tid + 256*q;
        int r  = fi >> 5;
        int xp = fi & 31;
        float4 v = make_float4(0.f,0.f,0.f,0.f);
        if (tbase + r < nh) v = tsrc[fi];
        int xs = (2*xp) ^ (r & 30);          // bank swizzle, keeps float2-pair alignment
        *(float4*)&stg[r*CKD + xs] = v;
    }
    __syncthreads();
    float u[4][4];
    #pragma unroll
    for (int a=0;a<4;a++)
        #pragma unroll
        for (int j=0;j<4;j++) u[a][j]=0.f;
    for (int x = 0; x < 64; x++) {
        float4 p0 = *(float4*)&sof[x*CKD + tx*4];
        float4 p1 = *(float4*)&sof[x*CKD + tx*4 + 2];
        #pragma unroll
        for (int tj = 0; tj < 4; tj++) {
            int tt = ty*4 + tj;
            float2 cs = stg[tt*CKD + (x ^ (tt & 30))];
            u[tj][0] = fmaf(cs.x, p0.x, fmaf(cs.y, p0.y, u[tj][0]));
            u[tj][1] = fmaf(cs.x, p0.z, fmaf(cs.y, p0.w, u[tj][1]));
            u[tj][2] = fmaf(cs.x, p1.x, fmaf(cs.y, p1.y, u[tj][2]));
            u[tj][3] = fmaf(cs.x, p1.z, fmaf(cs.y, p1.w, u[tj][3]));
        }
    }
    #pragma unroll
    for (int tj = 0; tj < 4; tj++) {
        int t = tbase + ty*4 + tj;
        if (t < nh)
            *(float4*)(U + (size_t)t*CKD + tx*4) = make_float4(u[tj][0],u[tj][1],u[tj][2],u[tj][3]);
    }
}

// ---------------- coarsest-level linear: x @ T0_w.T + b
__global__ __launch_bounds__(256) void t0_k(const float* __restrict__ xin,
        const float* __restrict__ w, const float* __restrict__ bias,
        float* __restrict__ xout) {
    int idx = blockIdx.x*256 + threadIdx.x;
    if (idx >= BB*CKD) return;
    int m = idx & 7, c = (idx >> 3) & 7, b = idx >> 6;
    const float* xr = xin + (size_t)b*CKD + c*KK;
    float acc = bias[m];
    #pragma unroll
    for (int j = 0; j < 8; j++) acc = fmaf(xr[j], w[m*8+j], acc);
    xout[idx] = acc;
}

// ---------------- reconstruct one level: (x+Us, Ud) @ rc_e / rc_o, interleave even/odd
__global__ __launch_bounds__(256) void recon_k(const float* __restrict__ xin,
        const float* __restrict__ us, const float* __restrict__ ud,
        const float* __restrict__ rce, const float* __restrict__ rco,
        float* __restrict__ xout, int nh) {
    int idx = blockIdx.x*256 + threadIdx.x;
    if (idx >= BB*nh*CC) return;
    int c = idx & 7;
    int t = (idx >> 3) % nh;
    int b = idx / (nh*CC);
    size_t base = ((size_t)b*nh + t)*CKD + c*KK;
    float xc[16];
    float4 a0 = ld4(xin+base), a1 = ld4(xin+base+4);
    float4 u0 = ld4(us+base),  u1 = ld4(us+base+4);
    float4 d0 = ld4(ud+base),  d1 = ld4(ud+base+4);
    xc[0]=a0.x+u0.x; xc[1]=a0.y+u0.y; xc[2]=a0.z+u0.z; xc[3]=a0.w+u0.w;
    xc[4]=a1.x+u1.x; xc[5]=a1.y+u1.y; xc[6]=a1.z+u1.z; xc[7]=a1.w+u1.w;
    xc[8]=d0.x;  xc[9]=d0.y;  xc[10]=d0.z; xc[11]=d0.w;
    xc[12]=d1.x; xc[13]=d1.y; xc[14]=d1.z; xc[15]=d1.w;
    float e[8], o2[8];
    #pragma unroll
    for (int m = 0; m < 8; m++) { e[m] = 0.f; o2[m] = 0.f; }
    #pragma unroll
    for (int j = 0; j < 16; j++) {
        float xv = xc[j];
        #pragma unroll
        for (int m = 0; m < 8; m++) {
            e[m]  = fmaf(xv, rce[j*8+m], e[m]);
            o2[m] = fmaf(xv, rco[j*8+m], o2[m]);
        }
    }
    size_t ob = ((size_t)b*2*nh + 2*t)*CKD + c*KK;
    *(float4*)(xout+ob)      = make_float4(e[0],e[1],e[2],e[3]);
    *(float4*)(xout+ob+4)    = make_float4(e[4],e[5],e[6],e[7]);
    *(float4*)(xout+ob+64)   = make_float4(o2[0],o2[1],o2[2],o2[3]);
    *(float4*)(xout+ob+68)   = make_float4(o2[4],o2[5],o2[6],o2[7]);
}

extern "C" void kernel_launch(void* const* d_in, const int* in_sizes, int n_in,
                              void* d_out, int out_size, void* d_ws, size_t ws_size,
                              hipStream_t stream) {
    const float* x   = (const float*)d_in[0];
    const float* wAr = (const float*)d_in[1];
    const float* wAi = (const float*)d_in[2];
    const float* wBr = (const float*)d_in[3];
    const float* wBi = (const float*)d_in[4];
    const float* wCr = (const float*)d_in[5];
    const float* wCi = (const float*)d_in[6];
    const float* T0w = (const float*)d_in[7];
    const float* T0b = (const float*)d_in[8];
    const float* ecs = (const float*)d_in[9];
    const float* ecd = (const float*)d_in[10];
    const float* rce = (const float*)d_in[11];
    const float* rco = (const float*)d_in[12];
    float* out = (float*)d_out;
    float* wsf = (float*)d_ws;

    // workspace layout (floats): trig tables | xf_d | xf_s | of_ud | of_us | x_t0 | rb0 | rb1
    float2* tbl = (float2*)wsf;
    size_t p = 1048448;                         // 524,224 float2 of tables
    float2* xfd  = (float2*)(wsf + p); p += 262144;
    float2* xfs  = (float2*)(wsf + p); p += 262144;
    float2* ofud = (float2*)(wsf + p); p += 262144;
    float2* ofus = (float2*)(wsf + p); p += 262144;
    float*  xt0  = wsf + p; p += 2048;
    float*  rb0  = wsf + p; p += 4194304;
    float*  rb1  = wsf + p; p += 8388608;
    (void)ws_size; (void)in_sizes; (void)n_in; (void)out_size;

    size_t udo[13], uso[13];
    {
        size_t a = 16777216ull;                 // after x region [B,8192,64]
        for (int i = 0; i < 13; i++) { udo[i] = a; a += 2048ull * (size_t)(4096u >> i); }
        for (int i = 0; i < 13; i++) { uso[i] = a; a += 2048ull * (size_t)(4096u >> i); }
    }

    gen_tbl_k<<<dim3(1024, 13), 256, 0, stream>>>(tbl);

    for (int i = 0; i < 13; i++) {
        int nh = 4096 >> i;
        int l = nh/2 + 1; if (l > 64) l = 64;
        size_t tboff = 64ull * (8192u - (8192u >> i));
        const float* xin_l = (i == 0) ? x : (out + uso[i-1]);
        int tot = BB * nh * CC;
        // stage d into Ud slot, s into Us slot (overwritten by inverse later)
        decomp_k<<<(tot + 255)/256, 256, 0, stream>>>(xin_l, ecd, ecs, out + udo[i], out + uso[i], nh);
        if (i > 0) {
            // inverse of previous level (after its s was consumed by this decomp)
            int ph = 4096 >> (i-1);
            int lp = ph/2 + 1; if (lp > 64) lp = 64;
            size_t tbp = 64ull * (8192u - (8192u >> (i-1)));
            fft_inv_k<<<dim3((ph + 63)/64, BB, 2), 256, 0, stream>>>(
                ofud, ofus, tbl + tbp, out + udo[i-1], out + uso[i-1], ph, lp);
        }
        hipMemsetAsync(xfd, 0, 2097152, stream);   // zero xf_d + xf_s (adjacent)
        int tiles = (nh + 63)/64;
        int chunks = tiles < 8 ? tiles : 8;
        int tpc = (tiles + chunks - 1)/chunks;
        fft_fwd_k<<<dim3(chunks, BB, 2), 256, 0, stream>>>(
            out + udo[i], out + uso[i], tbl + tboff, xfd, xfs, nh, tpc);
        mix_k<<<l, 256, 0, stream>>>(xfd, xfs, wAr, wAi, wBr, wBi, wCr, wCi, ofud, ofus, nh);
    }
    t0_k<<<(BB*CKD + 255)/256, 256, 0, stream>>>(out + uso[12], T0w, T0b, xt0);
    {
        size_t tbp = 64ull * (8192u - (8192u >> 12));
        fft_inv_k<<<dim3(1, BB, 2), 256, 0, stream>>>(ofud, ofus, tbl + tbp,
                                                      out + udo[12], out + uso[12], 1, 1);
    }
    const float* rin = xt0;
    for (int i = 12; i >= 0; i--) {
        int nh = 4096 >> i;
        float* ro = (i == 0) ? out : ((i & 1) ? rb1 : rb0);
        int tot = BB * nh * CC;
        recon_k<<<(tot + 255)/256, 256, 0, stream>>>(rin, out + uso[i], out + udo[i], rce, rco, ro, nh);
        rin = ro;
    }
}

// Round 2
// 1248.362 us; speedup vs baseline: 1.4068x; 1.4068x over previous
//
#include <hip/hip_runtime.h>

#define BB 32
#define CKD 64
#define CC 8
#define KK 8
#define TT 64

static __device__ __forceinline__ float4 ld4(const float* p){ return *(const float4*)p; }

// ---------------- trig tables: per level, tbl[t*64+x] = (cos, sin)(2*pi*x*t/n_h), zero for x>=l
__global__ __launch_bounds__(256) void gen_tbl_k(float2* __restrict__ base) {
    int lev = blockIdx.y;
    int nh = 4096 >> lev;
    int idx = blockIdx.x * 256 + threadIdx.x;
    if (idx >= nh * 64) return;
    int t = idx >> 6, x = idx & 63;
    int l = nh / 2 + 1; if (l > 64) l = 64;
    float c = 0.f, s = 0.f;
    if (x < l) {
        int r = (x * t) & (nh - 1);
        float th = 6.283185307179586f * ((float)r / (float)nh);
        sincosf(th, &s, &c);
    }
    size_t off = 64ull * (8192u - (8192u >> lev));
    base[off + idx] = make_float2(c, s);
}

// ---------------- decompose: x[b,2t,c,:],x[b,2t+1,c,:] -> d,s via ec_d/ec_s (16x8)
__global__ __launch_bounds__(256) void decomp_k(const float* __restrict__ xin,
        const float* __restrict__ ecd, const float* __restrict__ ecs,
        float* __restrict__ dslot, float* __restrict__ sslot, int nh) {
    int idx = blockIdx.x * 256 + threadIdx.x;
    if (idx >= BB * nh * CC) return;
    int c = idx & 7;
    int t = (idx >> 3) % nh;
    int b = idx / (nh * CC);
    const float* p0 = xin + ((size_t)b * 2 * nh + 2 * t) * CKD + c * KK;
    float xa[16];
    float4 v;
    v = ld4(p0);      xa[0]=v.x; xa[1]=v.y; xa[2]=v.z; xa[3]=v.w;
    v = ld4(p0+4);    xa[4]=v.x; xa[5]=v.y; xa[6]=v.z; xa[7]=v.w;
    v = ld4(p0+64);   xa[8]=v.x; xa[9]=v.y; xa[10]=v.z; xa[11]=v.w;
    v = ld4(p0+68);   xa[12]=v.x; xa[13]=v.y; xa[14]=v.z; xa[15]=v.w;
    float dd[8], ss[8];
    #pragma unroll
    for (int m = 0; m < 8; m++) { dd[m] = 0.f; ss[m] = 0.f; }
    #pragma unroll
    for (int j = 0; j < 16; j++) {
        float xv = xa[j];
        #pragma unroll
        for (int m = 0; m < 8; m++) {
            dd[m] = fmaf(xv, ecd[j*8+m], dd[m]);
            ss[m] = fmaf(xv, ecs[j*8+m], ss[m]);
        }
    }
    size_t ob = ((size_t)b * nh + t) * CKD + c * KK;
    *(float4*)(dslot+ob)   = make_float4(dd[0],dd[1],dd[2],dd[3]);
    *(float4*)(dslot+ob+4) = make_float4(dd[4],dd[5],dd[6],dd[7]);
    *(float4*)(sslot+ob)   = make_float4(ss[0],ss[1],ss[2],ss[3]);
    *(float4*)(sslot+ob+4) = make_float4(ss[4],ss[5],ss[6],ss[7]);
}

// ---------------- forward truncated DFT: xf[b,x,i] = sum_t v[b,t,i]*(cos, -sin)
// block = (chunk, b, which-of-d/s); partial results per chunk, no atomics
__global__ __launch_bounds__(256) void fft_fwd_k(const float* __restrict__ vd,
        const float* __restrict__ vs, const float2* __restrict__ tbl,
        float2* __restrict__ xfd, float2* __restrict__ xfs,
        float2* __restrict__ xfp,
        int nh, int tpc) {
    __shared__ float4 vt4[TT*CKD/4];   // 16 KB  value tile [t][i]
    __shared__ float4 tg4[TT*CKD/2];   // 32 KB  trig tile  [t][x] (float2)
    float* vt = (float*)vt4;
    float2* tg = (float2*)tg4;
    int b = blockIdx.y;
    const float* V = (blockIdx.z ? vs : vd) + (size_t)b * nh * CKD;
    float2* XF = (blockIdx.z ? xfs : xfd) + (size_t)b * 64 * 64;
    int tid = threadIdx.x;
    int tx = tid & 15, ty = tid >> 4;
    int tiles = (nh + TT - 1) / TT;
    int tile0 = blockIdx.x * tpc;
    int tile1 = tile0 + tpc; if (tile1 > tiles) tile1 = tiles;
    float2 acc[4][4];
    #pragma unroll
    for (int a = 0; a < 4; a++)
        #pragma unroll
        for (int i = 0; i < 4; i++) acc[a][i] = make_float2(0.f, 0.f);
    for (int tile = tile0; tile < tile1; tile++) {
        int tbase = tile * TT;
        __syncthreads();
        #pragma unroll
        for (int q = 0; q < 4; q++) {
            int fi = tid + 256*q;
            int r = fi >> 4;
            float4 v = make_float4(0.f,0.f,0.f,0.f);
            if (tbase + r < nh) v = ld4(V + (size_t)(tbase + r)*CKD + (fi & 15)*4);
            vt4[fi] = v;
        }
        const float4* tsrc = (const float4*)(tbl + (size_t)tbase * CKD);
        #pragma unroll
        for (int q = 0; q < 8; q++) {
            int fi = tid + 256*q;
            int r = fi >> 5;
            float4 v = make_float4(0.f,0.f,0.f,0.f);
            if (tbase + r < nh) v = tsrc[fi];
            tg4[fi] = v;
        }
        __syncthreads();
        #pragma unroll 4
        for (int t = 0; t < TT; t++) {
            float4 vv  = *(float4*)&vt[t*CKD + tx*4];
            float4 c01 = *(float4*)&tg[t*CKD + ty*4];
            float4 c23 = *(float4*)&tg[t*CKD + ty*4 + 2];
            float cx[4] = {c01.x, c01.z, c23.x, c23.z};
            float sx[4] = {c01.y, c01.w, c23.y, c23.w};
            float vr[4] = {vv.x, vv.y, vv.z, vv.w};
            #pragma unroll
            for (int a = 0; a < 4; a++)
                #pragma unroll
                for (int i = 0; i < 4; i++) {
                    acc[a][i].x = fmaf(cx[a],  vr[i], acc[a][i].x);
                    acc[a][i].y = fmaf(-sx[a], vr[i], acc[a][i].y);
                }
        }
    }
    int x0 = ty*4, i0 = tx*4;
    if (gridDim.x == 1) {
        #pragma unroll
        for (int a = 0; a < 4; a++)
            #pragma unroll
            for (int i = 0; i < 4; i++)
                XF[(x0+a)*64 + i0 + i] = acc[a][i];
    } else {
        float2* XFP = xfp + (((size_t)blockIdx.x*BB + b)*2 + blockIdx.z)*4096;
        #pragma unroll
        for (int a = 0; a < 4; a++)
            #pragma unroll
            for (int i = 0; i < 4; i++)
                XFP[(x0+a)*64 + i0 + i] = acc[a][i];
    }
}

// ---------------- sum the per-chunk partials into xfd/xfs
__global__ __launch_bounds__(256) void reduce_k(const float2* __restrict__ xfp,
        float2* __restrict__ xfd, float2* __restrict__ xfs, int chunks) {
    int e = blockIdx.x * 256 + threadIdx.x;      // e < BB*2*4096
    if (e >= BB * 2 * 4096) return;
    int j = e & 4095;
    int which = (e >> 12) & 1;
    int b = e >> 13;
    size_t base = (((size_t)b)*2 + which)*4096 + j;
    size_t stride = (size_t)BB*2*4096;
    float2 a = xfp[base];
    for (int c = 1; c < chunks; c++) {
        float2 p = xfp[base + (size_t)c*stride];
        a.x += p.x; a.y += p.y;
    }
    (which ? xfs : xfd)[(size_t)b*4096 + j] = a;
}

// ---------------- spectral mix: per mode x, of = xf * W (complex), write (A, Bn) pre-scaled for irfft
__global__ __launch_bounds__(256) void mix_k(const float2* __restrict__ xfd,
        const float2* __restrict__ xfs,
        const float* __restrict__ wAr, const float* __restrict__ wAi,
        const float* __restrict__ wBr, const float* __restrict__ wBi,
        const float* __restrict__ wCr, const float* __restrict__ wCi,
        float2* __restrict__ ofud, float2* __restrict__ ofus, int nh) {
    int x = blockIdx.x;
    int tid = threadIdx.x;
    int o = tid & 63, wq = tid >> 6;
    __shared__ float2 sxd[BB*CKD];     // 16 KB
    __shared__ float2 sxs[BB*CKD];     // 16 KB
    __shared__ float  swt[6][16*CKD];  // 24 KB
    for (int q = tid; q < BB*CKD; q += 256) {
        int b = q >> 6, i = q & 63;
        sxd[q] = xfd[((size_t)b*64 + x)*64 + i];
        sxs[q] = xfs[((size_t)b*64 + x)*64 + i];
    }
    float2 aud[8], aus[8];
    #pragma unroll
    for (int j=0;j<8;j++){ aud[j]=make_float2(0.f,0.f); aus[j]=make_float2(0.f,0.f); }
    for (int ic = 0; ic < 4; ic++) {
        __syncthreads();
        for (int q = tid; q < 16*CKD; q += 256) {
            int ii = q >> 6, oo = q & 63;
            size_t a = ((size_t)(ic*16+ii)*64 + oo)*64 + x;
            swt[0][q] = wAr[a]; swt[1][q] = wAi[a];
            swt[2][q] = wBr[a]; swt[3][q] = wBi[a];
            swt[4][q] = wCr[a]; swt[5][q] = wCi[a];
        }
        __syncthreads();
        #pragma unroll 4
        for (int ii = 0; ii < 16; ii++) {
            float ar = swt[0][ii*64+o], ai_ = swt[1][ii*64+o];
            float br = swt[2][ii*64+o], bi_ = swt[3][ii*64+o];
            float cr = swt[4][ii*64+o], ci_ = swt[5][ii*64+o];
            int i = ic*16 + ii;
            #pragma unroll
            for (int j = 0; j < 8; j++) {
                float2 xd = sxd[(wq*8+j)*64 + i];
                float2 xs = sxs[(wq*8+j)*64 + i];
                aud[j].x += xd.x*ar - xd.y*ai_ + xs.x*br - xs.y*bi_;
                aud[j].y += xd.x*ai_ + xd.y*ar + xs.x*bi_ + xs.y*br;
                aus[j].x += xd.x*cr - xd.y*ci_;
                aus[j].y += xd.x*ci_ + xd.y*cr;
            }
        }
    }
    float w = (x == 0 || 2*x == nh) ? 1.f : 2.f;   // irfft doubling; DC/Nyquist not doubled
    float sc = w / (float)nh;
    #pragma unroll
    for (int j = 0; j < 8; j++) {
        int b = wq*8 + j;
        size_t a = ((size_t)b*64 + x)*64 + o;
        ofud[a] = make_float2(sc*aud[j].x, -sc*aud[j].y);   // (A, Bn)
        ofus[a] = make_float2(sc*aus[j].x, -sc*aus[j].y);
    }
}

// ---------------- inverse truncated DFT: u[b,t,o] = sum_x A[x,o]*cos + Bn[x,o]*sin
__global__ __launch_bounds__(256) void fft_inv_k(const float2* __restrict__ ofud,
        const float2* __restrict__ ofus, const float2* __restrict__ tbl,
        float* __restrict__ uds, float* __restrict__ uss,
        int nh, int l) {
    __shared__ float4 sof4[64*CKD/2];  // 32 KB  [x][o] (A,Bn)
    __shared__ float4 stg4[TT*CKD/2];  // 32 KB  trig tile, XOR-swizzled rows
    float2* sof = (float2*)sof4;
    float2* stg = (float2*)stg4;
    int b = blockIdx.y;
    const float2* OF = (blockIdx.z ? ofus : ofud) + (size_t)b * 64 * 64;
    float* U = (blockIdx.z ? uss : uds) + (size_t)b * nh * CKD;
    int tid = threadIdx.x;
    int tx = tid & 15, ty = tid >> 4;
    int tbase = blockIdx.x * TT;
    #pragma unroll
    for (int q = 0; q < 8; q++) {
        int fi = tid + 256*q;
        int x = fi >> 5;
        float4 v = make_float4(0.f,0.f,0.f,0.f);
        if (x < l) v = ((const float4*)OF)[fi];
        sof4[fi] = v;
    }
    const float4* tsrc = (const float4*)(tbl + (size_t)tbase * CKD);
    #pragma unroll
    for (int q = 0; q < 8; q++) {
        int fi = tid + 256*q;
        int r  = fi >> 5;
        int xp = fi & 31;
        float4 v = make_float4(0.f,0.f,0.f,0.f);
        if (tbase + r < nh) v = tsrc[fi];
        int xs = (2*xp) ^ (r & 30);          // bank swizzle, keeps float2-pair alignment
        *(float4*)&stg[r*CKD + xs] = v;
    }
    __syncthreads();
    float u[4][4];
    #pragma unroll
    for (int a=0;a<4;a++)
        #pragma unroll
        for (int j=0;j<4;j++) u[a][j]=0.f;
    for (int x = 0; x < 64; x++) {
        float4 p0 = *(float4*)&sof[x*CKD + tx*4];
        float4 p1 = *(float4*)&sof[x*CKD + tx*4 + 2];
        #pragma unroll
        for (int tj = 0; tj < 4; tj++) {
            int tt = ty*4 + tj;
            float2 cs = stg[tt*CKD + (x ^ (tt & 30))];
            u[tj][0] = fmaf(cs.x, p0.x, fmaf(cs.y, p0.y, u[tj][0]));
            u[tj][1] = fmaf(cs.x, p0.z, fmaf(cs.y, p0.w, u[tj][1]));
            u[tj][2] = fmaf(cs.x, p1.x, fmaf(cs.y, p1.y, u[tj][2]));
            u[tj][3] = fmaf(cs.x, p1.z, fmaf(cs.y, p1.w, u[tj][3]));
        }
    }
    #pragma unroll
    for (int tj = 0; tj < 4; tj++) {
        int t = tbase + ty*4 + tj;
        if (t < nh)
            *(float4*)(U + (size_t)t*CKD + tx*4) = make_float4(u[tj][0],u[tj][1],u[tj][2],u[tj][3]);
    }
}

// ---------------- coarsest-level linear: x @ T0_w.T + b
__global__ __launch_bounds__(256) void t0_k(const float* __restrict__ xin,
        const float* __restrict__ w, const float* __restrict__ bias,
        float* __restrict__ xout) {
    int idx = blockIdx.x*256 + threadIdx.x;
    if (idx >= BB*CKD) return;
    int m = idx & 7, c = (idx >> 3) & 7, b = idx >> 6;
    const float* xr = xin + (size_t)b*CKD + c*KK;
    float acc = bias[m];
    #pragma unroll
    for (int j = 0; j < 8; j++) acc = fmaf(xr[j], w[m*8+j], acc);
    xout[idx] = acc;
}

// ---------------- reconstruct one level: (x+Us, Ud) @ rc_e / rc_o, interleave even/odd
__global__ __launch_bounds__(256) void recon_k(const float* __restrict__ xin,
        const float* __restrict__ us, const float* __restrict__ ud,
        const float* __restrict__ rce, const float* __restrict__ rco,
        float* __restrict__ xout, int nh) {
    int idx = blockIdx.x*256 + threadIdx.x;
    if (idx >= BB*nh*CC) return;
    int c = idx & 7;
    int t = (idx >> 3) % nh;
    int b = idx / (nh*CC);
    size_t base = ((size_t)b*nh + t)*CKD + c*KK;
    float xc[16];
    float4 a0 = ld4(xin+base), a1 = ld4(xin+base+4);
    float4 u0 = ld4(us+base),  u1 = ld4(us+base+4);
    float4 d0 = ld4(ud+base),  d1 = ld4(ud+base+4);
    xc[0]=a0.x+u0.x; xc[1]=a0.y+u0.y; xc[2]=a0.z+u0.z; xc[3]=a0.w+u0.w;
    xc[4]=a1.x+u1.x; xc[5]=a1.y+u1.y; xc[6]=a1.z+u1.z; xc[7]=a1.w+u1.w;
    xc[8]=d0.x;  xc[9]=d0.y;  xc[10]=d0.z; xc[11]=d0.w;
    xc[12]=d1.x; xc[13]=d1.y; xc[14]=d1.z; xc[15]=d1.w;
    float e[8], o2[8];
    #pragma unroll
    for (int m = 0; m < 8; m++) { e[m] = 0.f; o2[m] = 0.f; }
    #pragma unroll
    for (int j = 0; j < 16; j++) {
        float xv = xc[j];
        #pragma unroll
        for (int m = 0; m < 8; m++) {
            e[m]  = fmaf(xv, rce[j*8+m], e[m]);
            o2[m] = fmaf(xv, rco[j*8+m], o2[m]);
        }
    }
    size_t ob = ((size_t)b*2*nh + 2*t)*CKD + c*KK;
    *(float4*)(xout+ob)      = make_float4(e[0],e[1],e[2],e[3]);
    *(float4*)(xout+ob+4)    = make_float4(e[4],e[5],e[6],e[7]);
    *(float4*)(xout+ob+64)   = make_float4(o2[0],o2[1],o2[2],o2[3]);
    *(float4*)(xout+ob+68)   = make_float4(o2[4],o2[5],o2[6],o2[7]);
}

extern "C" void kernel_launch(void* const* d_in, const int* in_sizes, int n_in,
                              void* d_out, int out_size, void* d_ws, size_t ws_size,
                              hipStream_t stream) {
    const float* x   = (const float*)d_in[0];
    const float* wAr = (const float*)d_in[1];
    const float* wAi = (const float*)d_in[2];
    const float* wBr = (const float*)d_in[3];
    const float* wBi = (const float*)d_in[4];
    const float* wCr = (const float*)d_in[5];
    const float* wCi = (const float*)d_in[6];
    const float* T0w = (const float*)d_in[7];
    const float* T0b = (const float*)d_in[8];
    const float* ecs = (const float*)d_in[9];
    const float* ecd = (const float*)d_in[10];
    const float* rce = (const float*)d_in[11];
    const float* rco = (const float*)d_in[12];
    float* out = (float*)d_out;
    float* wsf = (float*)d_ws;

    // workspace layout (floats): trig tables | xf_d | xf_s | of_ud | of_us | x_t0 | rb0 | rb1
    // rb0 doubles as the fft_fwd partial buffer (only live during decomposition).
    float2* tbl = (float2*)wsf;
    size_t p = 1048448;                         // 524,224 float2 of tables
    float2* xfd  = (float2*)(wsf + p); p += 262144;
    float2* xfs  = (float2*)(wsf + p); p += 262144;
    float2* ofud = (float2*)(wsf + p); p += 262144;
    float2* ofus = (float2*)(wsf + p); p += 262144;
    float*  xt0  = wsf + p; p += 2048;
    float*  rb0  = wsf + p; p += 4194304;       // == 8 chunks * 32 b * 2 * 4096 float2
    float*  rb1  = wsf + p; p += 8388608;
    float2* xfp  = (float2*)rb0;
    (void)ws_size; (void)in_sizes; (void)n_in; (void)out_size;

    size_t udo[13], uso[13];
    {
        size_t a = 16777216ull;                 // after x region [B,8192,64]
        for (int i = 0; i < 13; i++) { udo[i] = a; a += 2048ull * (size_t)(4096u >> i); }
        for (int i = 0; i < 13; i++) { uso[i] = a; a += 2048ull * (size_t)(4096u >> i); }
    }

    gen_tbl_k<<<dim3(1024, 13), 256, 0, stream>>>(tbl);

    for (int i = 0; i < 13; i++) {
        int nh = 4096 >> i;
        int l = nh/2 + 1; if (l > 64) l = 64;
        size_t tboff = 64ull * (8192u - (8192u >> i));
        const float* xin_l = (i == 0) ? x : (out + uso[i-1]);
        int tot = BB * nh * CC;
        // stage d into Ud slot, s into Us slot (overwritten by inverse later)
        decomp_k<<<(tot + 255)/256, 256, 0, stream>>>(xin_l, ecd, ecs, out + udo[i], out + uso[i], nh);
        if (i > 0) {
            // inverse of previous level (after its s was consumed by this decomp)
            int ph = 4096 >> (i-1);
            int lp = ph/2 + 1; if (lp > 64) lp = 64;
            size_t tbp = 64ull * (8192u - (8192u >> (i-1)));
            fft_inv_k<<<dim3((ph + 63)/64, BB, 2), 256, 0, stream>>>(
                ofud, ofus, tbl + tbp, out + udo[i-1], out + uso[i-1], ph, lp);
        }
        int tiles = (nh + 63)/64;
        int chunks = tiles < 8 ? tiles : 8;
        int tpc = (tiles + chunks - 1)/chunks;
        fft_fwd_k<<<dim3(chunks, BB, 2), 256, 0, stream>>>(
            out + udo[i], out + uso[i], tbl + tboff, xfd, xfs, xfp, nh, tpc);
        if (chunks > 1)
            reduce_k<<<1024, 256, 0, stream>>>(xfp, xfd, xfs, chunks);
        mix_k<<<l, 256, 0, stream>>>(xfd, xfs, wAr, wAi, wBr, wBi, wCr, wCi, ofud, ofus, nh);
    }
    t0_k<<<(BB*CKD + 255)/256, 256, 0, stream>>>(out + uso[12], T0w, T0b, xt0);
    {
        size_t tbp = 64ull * (8192u - (8192u >> 12));
        fft_inv_k<<<dim3(1, BB, 2), 256, 0, stream>>>(ofud, ofus, tbl + tbp,
                                                      out + udo[12], out + uso[12], 1, 1);
    }
    const float* rin = xt0;
    for (int i = 12; i >= 0; i--) {
        int nh = 4096 >> i;
        float* ro = (i == 0) ? out : ((i & 1) ? rb1 : rb0);
        int tot = BB * nh * CC;
        recon_k<<<(tot + 255)/256, 256, 0, stream>>>(rin, out + uso[i], out + udo[i], rce, rco, ro, nh);
        rin = ro;
    }
}

// Round 3
// 638.252 us; speedup vs baseline: 2.7516x; 1.9559x over previous
//
#include <hip/hip_runtime.h>

#define BB 32
#define CKD 64
#define CC 8
#define KK 8
#define TT 64

// level tables (compile-time; N=8192, 13 levels)
__device__ const int D_CB[14] = {0,16,32,48,56,60,62,63,64,65,66,67,68,69};   // fwd chunk prefix
__device__ const int D_TILES[13] = {64,32,16,8,4,2,1,1,1,1,1,1,1};
__device__ const int D_TB[14] = {0,64,96,112,120,124,126,127,128,129,130,131,132,133}; // inv tile prefix
__device__ const int D_LS[14] = {0,64,128,192,256,320,384,417,434,443,448,451,453,454}; // mix l prefix
__device__ const int D_L[13]  = {64,64,64,64,64,64,33,17,9,5,3,2,1};

static __device__ __forceinline__ float4 ld4(const float* p){ return *(const float4*)p; }
static __device__ __forceinline__ size_t d_udo(int i){ return 33554432ull - (16777216u >> i); }
static __device__ __forceinline__ size_t d_uso(int i){ return 50329600ull - (16777216u >> i); }

// ---------------- trig tables: per level, tbl[t*64+x] = (cos, sin)(2*pi*x*t/n_h)
__global__ __launch_bounds__(256) void gen_tbl_k(float2* __restrict__ base) {
    int lev = blockIdx.y;
    int nh = 4096 >> lev;
    int idx = blockIdx.x * 256 + threadIdx.x;
    if (idx >= nh * 64) return;
    int t = idx >> 6, x = idx & 63;
    int l = nh / 2 + 1; if (l > 64) l = 64;
    float c = 0.f, s = 0.f;
    if (x < l) {
        int r = (x * t) & (nh - 1);
        float th = 6.283185307179586f * ((float)r / (float)nh);
        sincosf(th, &s, &c);
    }
    size_t off = 64ull * (8192u - (8192u >> lev));
    base[off + idx] = make_float2(c, s);
}

// ---------------- decompose: x[b,2t,c,:],x[b,2t+1,c,:] -> d,s via ec_d/ec_s (16x8)
__global__ __launch_bounds__(256) void decomp_k(const float* __restrict__ xin,
        const float* __restrict__ ecd, const float* __restrict__ ecs,
        float* __restrict__ dslot, float* __restrict__ sslot, int nh) {
    int idx = blockIdx.x * 256 + threadIdx.x;
    if (idx >= BB * nh * CC) return;
    int c = idx & 7;
    int t = (idx >> 3) % nh;
    int b = idx / (nh * CC);
    const float* p0 = xin + ((size_t)b * 2 * nh + 2 * t) * CKD + c * KK;
    float xa[16];
    float4 v;
    v = ld4(p0);      xa[0]=v.x; xa[1]=v.y; xa[2]=v.z; xa[3]=v.w;
    v = ld4(p0+4);    xa[4]=v.x; xa[5]=v.y; xa[6]=v.z; xa[7]=v.w;
    v = ld4(p0+64);   xa[8]=v.x; xa[9]=v.y; xa[10]=v.z; xa[11]=v.w;
    v = ld4(p0+68);   xa[12]=v.x; xa[13]=v.y; xa[14]=v.z; xa[15]=v.w;
    float dd[8], ss[8];
    #pragma unroll
    for (int m = 0; m < 8; m++) { dd[m] = 0.f; ss[m] = 0.f; }
    #pragma unroll
    for (int j = 0; j < 16; j++) {
        float xv = xa[j];
        #pragma unroll
        for (int m = 0; m < 8; m++) {
            dd[m] = fmaf(xv, ecd[j*8+m], dd[m]);
            ss[m] = fmaf(xv, ecs[j*8+m], ss[m]);
        }
    }
    size_t ob = ((size_t)b * nh + t) * CKD + c * KK;
    *(float4*)(dslot+ob)   = make_float4(dd[0],dd[1],dd[2],dd[3]);
    *(float4*)(dslot+ob+4) = make_float4(dd[4],dd[5],dd[6],dd[7]);
    *(float4*)(sslot+ob)   = make_float4(ss[0],ss[1],ss[2],ss[3]);
    *(float4*)(sslot+ob+4) = make_float4(ss[4],ss[5],ss[6],ss[7]);
}

// ---------------- forward truncated DFT, ALL levels in one launch.
// grid (69 chunk-slots, 32 b, 2 ds). Partial per slot, no atomics.
__global__ __launch_bounds__(256) void fft_fwd_all_k(const float* __restrict__ outbuf,
        const float2* __restrict__ tblb, float2* __restrict__ xfp) {
    __shared__ float4 vt4[TT*CKD/4];   // 16 KB  value tile [t][i]
    __shared__ float4 tg4[TT*CKD/2];   // 32 KB  trig tile  [t][x] (float2)
    float* vt = (float*)vt4;
    float2* tg = (float2*)tg4;
    int slot = blockIdx.x;
    int lvl = 0;
    while (lvl < 12 && slot >= D_CB[lvl+1]) lvl++;
    int nh = 4096 >> lvl;
    int tiles = D_TILES[lvl];
    int ch = D_CB[lvl+1] - D_CB[lvl];
    int tpc = tiles / ch;
    int b = blockIdx.y;
    const float* V = outbuf + (blockIdx.z ? d_uso(lvl) : d_udo(lvl)) + (size_t)b * nh * CKD;
    const float2* tbl = tblb + 64ull * (8192u - (8192u >> lvl));
    int tid = threadIdx.x;
    int tx = tid & 15, ty = tid >> 4;
    int tile0 = (slot - D_CB[lvl]) * tpc;
    int tile1 = tile0 + tpc;
    float2 acc[4][4];
    #pragma unroll
    for (int a = 0; a < 4; a++)
        #pragma unroll
        for (int i = 0; i < 4; i++) acc[a][i] = make_float2(0.f, 0.f);
    for (int tile = tile0; tile < tile1; tile++) {
        int tbase = tile * TT;
        __syncthreads();
        #pragma unroll
        for (int q = 0; q < 4; q++) {
            int fi = tid + 256*q;
            int r = fi >> 4;
            float4 v = make_float4(0.f,0.f,0.f,0.f);
            if (tbase + r < nh) v = ld4(V + (size_t)(tbase + r)*CKD + (fi & 15)*4);
            vt4[fi] = v;
        }
        const float4* tsrc = (const float4*)(tbl + (size_t)tbase * CKD);
        #pragma unroll
        for (int q = 0; q < 8; q++) {
            int fi = tid + 256*q;
            int r = fi >> 5;
            float4 v = make_float4(0.f,0.f,0.f,0.f);
            if (tbase + r < nh) v = tsrc[fi];
            tg4[fi] = v;
        }
        __syncthreads();
        #pragma unroll 4
        for (int t = 0; t < TT; t++) {
            float4 vv  = *(float4*)&vt[t*CKD + tx*4];
            float4 c01 = *(float4*)&tg[t*CKD + ty*4];
            float4 c23 = *(float4*)&tg[t*CKD + ty*4 + 2];
            float cx[4] = {c01.x, c01.z, c23.x, c23.z};
            float sx[4] = {c01.y, c01.w, c23.y, c23.w};
            float vr[4] = {vv.x, vv.y, vv.z, vv.w};
            #pragma unroll
            for (int a = 0; a < 4; a++)
                #pragma unroll
                for (int i = 0; i < 4; i++) {
                    acc[a][i].x = fmaf(cx[a],  vr[i], acc[a][i].x);
                    acc[a][i].y = fmaf(-sx[a], vr[i], acc[a][i].y);
                }
        }
    }
    int x0 = ty*4, i0 = tx*4;
    float2* XFP = xfp + (((size_t)slot*BB + b)*2 + blockIdx.z)*4096;
    #pragma unroll
    for (int a = 0; a < 4; a++)
        #pragma unroll
        for (int i = 0; i < 4; i++)
            XFP[(x0+a)*64 + i0 + i] = acc[a][i];
}

// ---------------- sum per-chunk partials into xf_all[level]
__global__ __launch_bounds__(256) void reduce_all_k(const float2* __restrict__ xfp,
        float2* __restrict__ xf_all) {
    int lvl = blockIdx.y;
    int e = blockIdx.x * 256 + threadIdx.x;      // e < BB*2*4096
    int j = e & 4095;
    int z = (e >> 12) & 1;
    int b = e >> 13;
    int c0 = D_CB[lvl], c1 = D_CB[lvl+1];
    size_t stride = (size_t)BB*2*4096;
    size_t base = (((size_t)c0*BB + b)*2 + z)*4096 + j;
    float2 a = xfp[base];
    for (int c = c0+1; c < c1; c++) {
        base += stride;
        float2 p = xfp[base];
        a.x += p.x; a.y += p.y;
    }
    xf_all[(size_t)lvl*262144 + ((size_t)b*2 + z)*4096 + j] = a;
}

// ---------------- spectral mix, ALL levels: block = (level, mode x)
__global__ __launch_bounds__(256) void mix_all_k(const float2* __restrict__ xf_all,
        const float* __restrict__ wAr, const float* __restrict__ wAi,
        const float* __restrict__ wBr, const float* __restrict__ wBi,
        const float* __restrict__ wCr, const float* __restrict__ wCi,
        float2* __restrict__ of_all) {
    int lvl = 0;
    while (lvl < 12 && (int)blockIdx.x >= D_LS[lvl+1]) lvl++;
    int x = blockIdx.x - D_LS[lvl];
    int nh = 4096 >> lvl;
    const float2* xfL = xf_all + (size_t)lvl*262144;
    float2* ofL = of_all + (size_t)lvl*262144;
    int tid = threadIdx.x;
    int o = tid & 63, wq = tid >> 6;
    __shared__ float2 sxd[BB*CKD];     // 16 KB
    __shared__ float2 sxs[BB*CKD];     // 16 KB
    __shared__ float  swt[6][16*CKD];  // 24 KB
    for (int q = tid; q < BB*CKD; q += 256) {
        int b = q >> 6, i = q & 63;
        sxd[q] = xfL[((size_t)b*2 + 0)*4096 + x*64 + i];
        sxs[q] = xfL[((size_t)b*2 + 1)*4096 + x*64 + i];
    }
    float2 aud[8], aus[8];
    #pragma unroll
    for (int j=0;j<8;j++){ aud[j]=make_float2(0.f,0.f); aus[j]=make_float2(0.f,0.f); }
    for (int ic = 0; ic < 4; ic++) {
        __syncthreads();
        for (int q = tid; q < 16*CKD; q += 256) {
            int ii = q >> 6, oo = q & 63;
            size_t a = ((size_t)(ic*16+ii)*64 + oo)*64 + x;
            swt[0][q] = wAr[a]; swt[1][q] = wAi[a];
            swt[2][q] = wBr[a]; swt[3][q] = wBi[a];
            swt[4][q] = wCr[a]; swt[5][q] = wCi[a];
        }
        __syncthreads();
        #pragma unroll 4
        for (int ii = 0; ii < 16; ii++) {
            float ar = swt[0][ii*64+o], ai_ = swt[1][ii*64+o];
            float br = swt[2][ii*64+o], bi_ = swt[3][ii*64+o];
            float cr = swt[4][ii*64+o], ci_ = swt[5][ii*64+o];
            int i = ic*16 + ii;
            #pragma unroll
            for (int j = 0; j < 8; j++) {
                float2 xd = sxd[(wq*8+j)*64 + i];
                float2 xs = sxs[(wq*8+j)*64 + i];
                aud[j].x += xd.x*ar - xd.y*ai_ + xs.x*br - xs.y*bi_;
                aud[j].y += xd.x*ai_ + xd.y*ar + xs.x*bi_ + xs.y*br;
                aus[j].x += xd.x*cr - xd.y*ci_;
                aus[j].y += xd.x*ci_ + xd.y*cr;
            }
        }
    }
    float w = (x == 0 || 2*x == nh) ? 1.f : 2.f;   // irfft doubling; DC/Nyquist not doubled
    float sc = w / (float)nh;
    #pragma unroll
    for (int j = 0; j < 8; j++) {
        int b = wq*8 + j;
        ofL[((size_t)b*2 + 0)*4096 + x*64 + o] = make_float2(sc*aud[j].x, -sc*aud[j].y);
        ofL[((size_t)b*2 + 1)*4096 + x*64 + o] = make_float2(sc*aus[j].x, -sc*aus[j].y);
    }
}

// ---------------- inverse truncated DFT, ALL levels: grid (133 tiles, 32 b, 2 ds)
__global__ __launch_bounds__(256) void fft_inv_all_k(const float2* __restrict__ of_all,
        const float2* __restrict__ tblb, float* __restrict__ outbuf) {
    __shared__ float4 sof4[64*CKD/2];  // 32 KB  [x][o] (A,Bn)
    __shared__ float4 stg4[TT*CKD/2];  // 32 KB  trig tile, XOR-swizzled rows
    float2* sof = (float2*)sof4;
    float2* stg = (float2*)stg4;
    int lvl = 0;
    while (lvl < 12 && (int)blockIdx.x >= D_TB[lvl+1]) lvl++;
    int tile = blockIdx.x - D_TB[lvl];
    int nh = 4096 >> lvl;
    int l = D_L[lvl];
    int b = blockIdx.y;
    const float2* OF = of_all + (size_t)lvl*262144 + ((size_t)b*2 + blockIdx.z)*4096;
    float* U = outbuf + (blockIdx.z ? d_uso(lvl) : d_udo(lvl)) + (size_t)b * nh * CKD;
    const float2* tbl = tblb + 64ull * (8192u - (8192u >> lvl));
    int tid = threadIdx.x;
    int tx = tid & 15, ty = tid >> 4;
    int tbase = tile * TT;
    #pragma unroll
    for (int q = 0; q < 8; q++) {
        int fi = tid + 256*q;
        int x = fi >> 5;
        float4 v = make_float4(0.f,0.f,0.f,0.f);
        if (x < l) v = ((const float4*)OF)[fi];
        sof4[fi] = v;
    }
    const float4* tsrc = (const float4*)(tbl + (size_t)tbase * CKD);
    #pragma unroll
    for (int q = 0; q < 8; q++) {
        int fi = tid + 256*q;
        int r  = fi >> 5;
        int xp = fi & 31;
        float4 v = make_float4(0.f,0.f,0.f,0.f);
        if (tbase + r < nh) v = tsrc[fi];
        int xs = (2*xp) ^ (r & 30);          // bank swizzle, keeps float2-pair alignment
        *(float4*)&stg[r*CKD + xs] = v;
    }
    __syncthreads();
    float u[4][4];
    #pragma unroll
    for (int a=0;a<4;a++)
        #pragma unroll
        for (int j=0;j<4;j++) u[a][j]=0.f;
    for (int x = 0; x < 64; x++) {
        float4 p0 = *(float4*)&sof[x*CKD + tx*4];
        float4 p1 = *(float4*)&sof[x*CKD + tx*4 + 2];
        #pragma unroll
        for (int tj = 0; tj < 4; tj++) {
            int tt = ty*4 + tj;
            float2 cs = stg[tt*CKD + (x ^ (tt & 30))];
            u[tj][0] = fmaf(cs.x, p0.x, fmaf(cs.y, p0.y, u[tj][0]));
            u[tj][1] = fmaf(cs.x, p0.z, fmaf(cs.y, p0.w, u[tj][1]));
            u[tj][2] = fmaf(cs.x, p1.x, fmaf(cs.y, p1.y, u[tj][2]));
            u[tj][3] = fmaf(cs.x, p1.z, fmaf(cs.y, p1.w, u[tj][3]));
        }
    }
    #pragma unroll
    for (int tj = 0; tj < 4; tj++) {
        int t = tbase + ty*4 + tj;
        if (t < nh)
            *(float4*)(U + (size_t)t*CKD + tx*4) = make_float4(u[tj][0],u[tj][1],u[tj][2],u[tj][3]);
    }
}

// ---------------- coarsest-level linear: x @ T0_w.T + b
__global__ __launch_bounds__(256) void t0_k(const float* __restrict__ xin,
        const float* __restrict__ w, const float* __restrict__ bias,
        float* __restrict__ xout) {
    int idx = blockIdx.x*256 + threadIdx.x;
    if (idx >= BB*CKD) return;
    int m = idx & 7, c = (idx >> 3) & 7, b = idx >> 6;
    const float* xr = xin + (size_t)b*CKD + c*KK;
    float acc = bias[m];
    #pragma unroll
    for (int j = 0; j < 8; j++) acc = fmaf(xr[j], w[m*8+j], acc);
    xout[idx] = acc;
}

// ---------------- reconstruct one level: (x+Us, Ud) @ rc_e / rc_o, interleave even/odd
__global__ __launch_bounds__(256) void recon_k(const float* __restrict__ xin,
        const float* __restrict__ us, const float* __restrict__ ud,
        const float* __restrict__ rce, const float* __restrict__ rco,
        float* __restrict__ xout, int nh) {
    int idx = blockIdx.x*256 + threadIdx.x;
    if (idx >= BB*nh*CC) return;
    int c = idx & 7;
    int t = (idx >> 3) % nh;
    int b = idx / (nh*CC);
    size_t base = ((size_t)b*nh + t)*CKD + c*KK;
    float xc[16];
    float4 a0 = ld4(xin+base), a1 = ld4(xin+base+4);
    float4 u0 = ld4(us+base),  u1 = ld4(us+base+4);
    float4 d0 = ld4(ud+base),  d1 = ld4(ud+base+4);
    xc[0]=a0.x+u0.x; xc[1]=a0.y+u0.y; xc[2]=a0.z+u0.z; xc[3]=a0.w+u0.w;
    xc[4]=a1.x+u1.x; xc[5]=a1.y+u1.y; xc[6]=a1.z+u1.z; xc[7]=a1.w+u1.w;
    xc[8]=d0.x;  xc[9]=d0.y;  xc[10]=d0.z; xc[11]=d0.w;
    xc[12]=d1.x; xc[13]=d1.y; xc[14]=d1.z; xc[15]=d1.w;
    float e[8], o2[8];
    #pragma unroll
    for (int m = 0; m < 8; m++) { e[m] = 0.f; o2[m] = 0.f; }
    #pragma unroll
    for (int j = 0; j < 16; j++) {
        float xv = xc[j];
        #pragma unroll
        for (int m = 0; m < 8; m++) {
            e[m]  = fmaf(xv, rce[j*8+m], e[m]);
            o2[m] = fmaf(xv, rco[j*8+m], o2[m]);
        }
    }
    size_t ob = ((size_t)b*2*nh + 2*t)*CKD + c*KK;
    *(float4*)(xout+ob)      = make_float4(e[0],e[1],e[2],e[3]);
    *(float4*)(xout+ob+4)    = make_float4(e[4],e[5],e[6],e[7]);
    *(float4*)(xout+ob+64)   = make_float4(o2[0],o2[1],o2[2],o2[3]);
    *(float4*)(xout+ob+68)   = make_float4(o2[4],o2[5],o2[6],o2[7]);
}

extern "C" void kernel_launch(void* const* d_in, const int* in_sizes, int n_in,
                              void* d_out, int out_size, void* d_ws, size_t ws_size,
                              hipStream_t stream) {
    const float* x   = (const float*)d_in[0];
    const float* wAr = (const float*)d_in[1];
    const float* wAi = (const float*)d_in[2];
    const float* wBr = (const float*)d_in[3];
    const float* wBi = (const float*)d_in[4];
    const float* wCr = (const float*)d_in[5];
    const float* wCi = (const float*)d_in[6];
    const float* T0w = (const float*)d_in[7];
    const float* T0b = (const float*)d_in[8];
    const float* ecs = (const float*)d_in[9];
    const float* ecd = (const float*)d_in[10];
    const float* rce = (const float*)d_in[11];
    const float* rco = (const float*)d_in[12];
    float* out = (float*)d_out;
    float* wsf = (float*)d_ws;

    // workspace layout (floats)
    float2* tbl = (float2*)wsf;
    size_t p = 1048448;                              // 524,224 float2 of tables
    float2* xf_all = (float2*)(wsf + p); p += 13ull*262144*2;   // 27 MB
    float2* of_all = (float2*)(wsf + p); p += 13ull*262144*2;   // 27 MB
    float*  xt0  = wsf + p; p += 2048;
    float*  rb0  = wsf + p; p += 4194304;
    float*  rb1  = wsf + p; p += 8388608;
    float2* xfp  = (float2*)(wsf + p); p += 69ull*BB*2*4096*2;  // 145 MB
    (void)ws_size; (void)in_sizes; (void)n_in; (void)out_size;

    size_t udo[13], uso[13];
    for (int i = 0; i < 13; i++) {
        udo[i] = 33554432ull - (16777216u >> i);
        uso[i] = 50329600ull - (16777216u >> i);
    }

    gen_tbl_k<<<dim3(1024, 13), 256, 0, stream>>>(tbl);

    // sequential decomposition chain (s feeds next level)
    for (int i = 0; i < 13; i++) {
        int nh = 4096 >> i;
        const float* xin_l = (i == 0) ? x : (out + uso[i-1]);
        int tot = BB * nh * CC;
        decomp_k<<<(tot + 255)/256, 256, 0, stream>>>(xin_l, ecd, ecs, out + udo[i], out + uso[i], nh);
    }
    // coarsest-level linear (reads s_12 before inv overwrites it)
    t0_k<<<(BB*CKD + 255)/256, 256, 0, stream>>>(out + uso[12], T0w, T0b, xt0);

    // all-levels spectral pipeline: fwd -> reduce -> mix -> inv
    fft_fwd_all_k<<<dim3(69, BB, 2), 256, 0, stream>>>(out, tbl, xfp);
    reduce_all_k<<<dim3(1024, 13), 256, 0, stream>>>(xfp, xf_all);
    mix_all_k<<<454, 256, 0, stream>>>(xf_all, wAr, wAi, wBr, wBi, wCr, wCi, of_all);
    fft_inv_all_k<<<dim3(133, BB, 2), 256, 0, stream>>>(of_all, tbl, out);

    // sequential reconstruction chain
    const float* rin = xt0;
    for (int i = 12; i >= 0; i--) {
        int nh = 4096 >> i;
        float* ro = (i == 0) ? out : ((i & 1) ? rb1 : rb0);
        int tot = BB * nh * CC;
        recon_k<<<(tot + 255)/256, 256, 0, stream>>>(rin, out + uso[i], out + udo[i], rce, rco, ro, nh);
        rin = ro;
    }
}